// Round 6
// baseline (408.160 us; speedup 1.0000x reference)
//
#include <hip/hip_runtime.h>
#include <hip/hip_bf16.h>
#include <hip/hip_fp8.h>

// ---------- types ----------
typedef __attribute__((ext_vector_type(4))) float  f32x4;
typedef __attribute__((ext_vector_type(8))) unsigned short u16x8;
typedef __attribute__((ext_vector_type(4))) unsigned short u16x4;
typedef long long f8x8;   // 8 fp8 values in 2 VGPRs (MFMA fp8 operand)

#define DIM 384
#define NE 8
#define HID 1536
#define NB 32
#define HW 1024
#define T_TOK 32768  // NB*HW

__device__ __forceinline__ unsigned short f2bf(float f) {
    unsigned int u = __float_as_uint(f);
    u = (u + 0x7fffu + ((u >> 16) & 1u)) >> 16;
    return (unsigned short)u;
}
__device__ __forceinline__ float bf2f(unsigned short u) {
    return __uint_as_float((unsigned int)u << 16);
}
__device__ __forceinline__ unsigned char f2fp8(float f) {
    __hip_fp8_e4m3 h(f);
    return (unsigned char)h.__x;
}

// ---------- K0: transpose fp32 [E][R][C] -> fp8 [E][C][R] ----------
__global__ __launch_bounds__(256) void k_transpose8(const float* __restrict__ src,
                                                    unsigned char* __restrict__ dst,
                                                    int R, int C) {
    int b = blockIdx.x;
    int ctiles = C >> 5;
    int rtiles = R >> 5;
    int ct = b % ctiles;
    int rt = (b / ctiles) % rtiles;
    int e  = b / (ctiles * rtiles);
    __shared__ float t[32][33];
    int tid = threadIdx.x;
    const float* s = src + (size_t)e * R * C;
    unsigned char* d = dst + (size_t)e * C * R;
#pragma unroll
    for (int k = 0; k < 4; ++k) {
        int idx = k * 256 + tid;
        int rr = idx >> 5, cc = idx & 31;
        t[rr][cc] = s[(size_t)(rt * 32 + rr) * C + ct * 32 + cc];
    }
    __syncthreads();
    // 256 threads = 32 cc x 8 row-quads; pack 4 fp8 -> u32 store
    int cc = tid >> 3, r4 = tid & 7;
    unsigned int pk = 0;
#pragma unroll
    for (int i = 0; i < 4; ++i)
        pk |= (unsigned int)f2fp8(t[r4 * 4 + i][cc]) << (8 * i);
    *(unsigned int*)&d[(size_t)(ct * 32 + cc) * R + rt * 32 + r4 * 4] = pk;
}

// ---------- K1: depthwise 7x7 conv, NCHW -> NCHW (xconv) ----------
__global__ __launch_bounds__(256) void k_conv(const float* __restrict__ in,
                                              const float* __restrict__ dw_w,
                                              const float* __restrict__ dw_b,
                                              float* __restrict__ xconv) {
    int nc = blockIdx.x;             // n*384 + c
    int c = nc % DIM;
    __shared__ float tile[38 * 38];
    __shared__ float wt[49];
    const float* plane = in + (size_t)nc * HW;
    int tid = threadIdx.x;
    if (tid < 49) wt[tid] = dw_w[c * 49 + tid];
    for (int idx = tid; idx < 38 * 38; idx += 256) {
        int ty = idx / 38, tx = idx % 38;
        int ih = ty - 3, iw = tx - 3;
        float v = 0.f;
        if ((unsigned)ih < 32u && (unsigned)iw < 32u) v = plane[ih * 32 + iw];
        tile[idx] = v;
    }
    __syncthreads();
    float bias = dw_b[c];
    int w = tid & 31, h0 = (tid >> 5) << 2;   // 4 consecutive h rows per thread
    float acc[4] = {bias, bias, bias, bias};
#pragma unroll
    for (int iy = 0; iy < 10; ++iy) {
        float r[7];
#pragma unroll
        for (int dx = 0; dx < 7; ++dx) r[dx] = tile[(h0 + iy) * 38 + w + dx];
#pragma unroll
        for (int o = 0; o < 4; ++o) {
            int dy = iy - o;
            if (dy >= 0 && dy < 7) {
                float a = 0.f;
#pragma unroll
                for (int dx = 0; dx < 7; ++dx) a += r[dx] * wt[dy * 7 + dx];
                acc[o] += a;
            }
        }
    }
    float* outp = xconv + (size_t)nc * HW;
#pragma unroll
    for (int o = 0; o < 4; ++o) outp[(h0 + o) * 32 + w] = acc[o];
}

// ---------- K2: LayerNorm + gate + top-2 routing (fp8 X out) ----------
__global__ __launch_bounds__(256) void k_ln_gate(const float* __restrict__ xconv,
                                                 const float* __restrict__ ln_g,
                                                 const float* __restrict__ ln_b,
                                                 const float* __restrict__ gate_w,
                                                 unsigned char* __restrict__ lnout,
                                                 int* __restrict__ lists,
                                                 float* __restrict__ wgts,
                                                 int* __restrict__ counts) {
    __shared__ float xs[32][385];
    __shared__ float gw[8][384];
    __shared__ float gls[384], bls[384];
    __shared__ int hcnt[8], hbase[8];
    __shared__ int lexp[32][2];
    __shared__ int lpos[32][2];
    __shared__ float lw[32][2];

    int b = blockIdx.x;
    int n = b >> 5;
    int hw0 = (b & 31) << 5;
    int tid = threadIdx.x;

    for (int i = tid; i < 384; i += 256) { gls[i] = ln_g[i]; bls[i] = ln_b[i]; }
    for (int i = tid; i < 8 * 384; i += 256) gw[i / 384][i % 384] = gate_w[i];
    if (tid < 8) hcnt[tid] = 0;

    const float* base = xconv + (size_t)n * DIM * HW + hw0;
#pragma unroll
    for (int k = 0; k < 48; ++k) {
        int idx = k * 256 + tid;
        int c = idx >> 5, j = idx & 31;
        xs[j][c] = base[(size_t)c * HW + j];
    }
    __syncthreads();

    int tok = tid >> 3, jj = tid & 7;     // 8 lanes per token
    float sum = 0.f, sq = 0.f;
#pragma unroll
    for (int k = 0; k < 48; ++k) {
        float v = xs[tok][jj + 8 * k];
        sum += v; sq += v * v;
    }
#pragma unroll
    for (int m = 1; m < 8; m <<= 1) { sum += __shfl_xor(sum, m); sq += __shfl_xor(sq, m); }
    float mu = sum * (1.f / 384.f);
    float var = sq * (1.f / 384.f) - mu * mu;
    float rstd = rsqrtf(var + 1e-6f);

    int tglob = n * HW + hw0 + tok;
    float p[8] = {0, 0, 0, 0, 0, 0, 0, 0};
#pragma unroll
    for (int k = 0; k < 48; ++k) {
        int c = jj + 8 * k;
        float v = (xs[tok][c] - mu) * rstd * gls[c] + bls[c];
        lnout[(size_t)tglob * DIM + c] = f2fp8(v);
#pragma unroll
        for (int e = 0; e < 8; ++e) p[e] += v * gw[e][c];
    }
#pragma unroll
    for (int e = 0; e < 8; ++e)
#pragma unroll
        for (int m = 1; m < 8; m <<= 1) p[e] += __shfl_xor(p[e], m);

    if (jj == 0) {
        int i0 = 0; float v0 = p[0];
#pragma unroll
        for (int e = 1; e < 8; ++e) if (p[e] > v0) { v0 = p[e]; i0 = e; }
        int i1 = -1; float v1 = -1e30f;
#pragma unroll
        for (int e = 0; e < 8; ++e) if (e != i0 && p[e] > v1) { v1 = p[e]; i1 = e; }
        float w0 = 1.f / (1.f + __expf(v1 - v0));
        float w1 = 1.f - w0;
        lexp[tok][0] = i0; lexp[tok][1] = i1;
        lw[tok][0] = w0;  lw[tok][1] = w1;
        lpos[tok][0] = atomicAdd(&hcnt[i0], 1);
        lpos[tok][1] = atomicAdd(&hcnt[i1], 1);
    }
    __syncthreads();
    if (tid < 8) hbase[tid] = atomicAdd(&counts[tid], hcnt[tid]);
    __syncthreads();
    if (jj == 0) {
#pragma unroll
        for (int s = 0; s < 2; ++s) {
            int e = lexp[tok][s];
            int pos = hbase[e] + lpos[tok][s];
            lists[e * T_TOK + pos] = (tglob << 1) | s;
            wgts[e * T_TOK + pos] = lw[tok][s];
        }
    }
}

// ---------- K3: gathered expert MLP, all-fp8 operands (GEMM1 -> gelu -> GEMM2) ----------
// v6: __launch_bounds__(512,1) -> 256-VGPR budget so the W1/W2 register preloads
//     actually stay resident (R5's (512,2) capped VGPR at 128 and the compiler
//     sank every preload to its use point -> serial L2-latency convoy).
__global__ __launch_bounds__(512, 1) void k_moe(const unsigned char* __restrict__ ln,
                                                const unsigned char* __restrict__ w1t, // [8][1536][384] fp8
                                                const unsigned char* __restrict__ w2t, // [8][384][1536] fp8
                                                const float* __restrict__ b1,
                                                const float* __restrict__ b2,
                                                const int* __restrict__ lists,
                                                const float* __restrict__ wgts,
                                                const int* __restrict__ counts,
                                                unsigned short* __restrict__ y0,
                                                unsigned short* __restrict__ y1) {
    int e    = blockIdx.x & 7;        // expert -> fixed XCD (round-robin dispatch)
    int tile = blockIdx.x >> 3;       // 0..255
    int cnt = counts[e];
    if (tile * 128 >= cnt) return;

    __shared__ unsigned char X[128][400];    // 51,200 B (row coeff 100 dw: b64 reads at 4-lane/bank-pair floor)
    __shared__ unsigned char Hs[128][136];   // 17,408 B (row coeff 34 dw: reads at floor)
    __shared__ int   ents[128];
    __shared__ float wrow[128];

    int tid = threadIdx.x;
    if (tid < 128) {
        int idx = tile * 128 + tid;
        if (idx < cnt) { ents[tid] = lists[e * T_TOK + idx]; wrow[tid] = wgts[e * T_TOK + idx]; }
        else           { ents[tid] = -1;                     wrow[tid] = 0.f; }
    }
    __syncthreads();

    // gather X rows (fp8, 384B/row, 4 lanes x 6 x 16B), non-temporal
    {
        int row = tid >> 2, q = tid & 3;
        int ent = ents[row];
        int tok = (ent < 0) ? 0 : (ent >> 1);
        const u16x8* src = (const u16x8*)(ln + (size_t)tok * DIM);
#pragma unroll
        for (int r = 0; r < 6; ++r)
            *(u16x8*)&X[row][(q + r * 4) * 16] = __builtin_nontemporal_load(&src[q + r * 4]);
    }
    __syncthreads();

    int wid = tid >> 6;          // 0..7
    int lane = tid & 63;
    int lr = lane & 15;          // A row (hid/dim) ; B col (token)
    int lq = lane >> 4;          // 0..3 (k-group of 8 fp8)

    // W1 A-frag: w1t[(e*HID + hc*128 + wid*16 + lr)*384 + k*32 + lq*8]  (bytes)
    const unsigned char* pw1 = w1t + ((size_t)e * HID + wid * 16 + lr) * DIM + lq * 8;
    // W2 A-frag: w2t[(e*DIM + wid*48 + nj*16 + lr)*1536 + hc*128 + k2*32 + lq*8]
    const unsigned char* pw2 = w2t + ((size_t)e * DIM + wid * 48 + lr) * HID + lq * 8;

    f32x4 Yacc[3][8] = {};   // [nj][m] : dims wid*48+nj*16+lq*4+r, token m*16+lr

    // prologue: W1 frags for hc=0
    f8x8 wall[12];
#pragma unroll
    for (int k = 0; k < 12; ++k) wall[k] = *(const f8x8*)(pw1 + k * 32);

    for (int hc = 0; hc < 12; ++hc) {
        // issue W2 frags for this hc now; consumed after GEMM1+gelu (latency hidden)
        f8x8 vall[12];
#pragma unroll
        for (int t = 0; t < 12; ++t) {
            int nj = t % 3, k2 = t / 3;
            vall[t] = *(const f8x8*)(pw2 + (size_t)nj * 16 * HID + hc * 128 + k2 * 32);
        }
        // ---- GEMM1: H^T = W1(hid,K) x X^T(token,K); lane: token=lr (col), hid=lq*4+r (row)
        f32x4 bv = *(const f32x4*)&b1[e * HID + hc * 128 + wid * 16 + lq * 4];
        f32x4 Hf[8];
#pragma unroll
        for (int m = 0; m < 8; ++m) Hf[m] = bv;
        __builtin_amdgcn_s_setprio(1);
#pragma unroll
        for (int k = 0; k < 12; ++k) {
#pragma unroll
            for (int m = 0; m < 8; ++m) {
                f8x8 a = *(const f8x8*)&X[m * 16 + lr][k * 32 + lq * 8];
                Hf[m] = __builtin_amdgcn_mfma_f32_16x16x32_fp8_fp8(wall[k], a, Hf[m], 0, 0, 0);
            }
        }
        __builtin_amdgcn_s_setprio(0);
        // ---- prefetch W1 frags for hc+1 (in flight across the barriers below)
        if (hc < 11) {
            const unsigned char* pn = pw1 + (size_t)(hc + 1) * 128 * DIM;
#pragma unroll
            for (int k = 0; k < 12; ++k) wall[k] = *(const f8x8*)(pn + k * 32);
        }
        // ---- gelu -> packed fp8 u32 write (lane holds 4 consecutive hid for token lr)
#pragma unroll
        for (int m = 0; m < 8; ++m) {
            unsigned int pk = 0;
#pragma unroll
            for (int r = 0; r < 4; ++r) {
                float v = Hf[m][r];
                float t = v * fmaf(v * v, -0.07135481627f, -1.5957691216f); // = -2z
                float g = v * __builtin_amdgcn_rcpf(1.f + __expf(t));
                pk |= (unsigned int)f2fp8(g) << (8 * r);
            }
            *(unsigned int*)&Hs[m * 16 + lr][wid * 16 + lq * 4] = pk;
        }
        // producer barrier: LDS drained, vmcnt NOT drained
        asm volatile("s_waitcnt lgkmcnt(0)" ::: "memory");
        __builtin_amdgcn_s_barrier();
        __builtin_amdgcn_sched_barrier(0);
        // ---- GEMM2: Y^T += W2(dim,K=128) x H^T(token,K)
        __builtin_amdgcn_s_setprio(1);
#pragma unroll
        for (int k2 = 0; k2 < 4; ++k2) {
#pragma unroll
            for (int m = 0; m < 8; ++m) {
                f8x8 h = *(const f8x8*)&Hs[m * 16 + lr][k2 * 32 + lq * 8];
#pragma unroll
                for (int nj = 0; nj < 3; ++nj) {
                    Yacc[nj][m] = __builtin_amdgcn_mfma_f32_16x16x32_fp8_fp8(vall[k2 * 3 + nj], h, Yacc[nj][m], 0, 0, 0);
                }
            }
        }
        __builtin_amdgcn_s_setprio(0);
        // consumer barrier: Hs reads retired before next overwrite
        asm volatile("s_waitcnt lgkmcnt(0)" ::: "memory");
        __builtin_amdgcn_s_barrier();
        __builtin_amdgcn_sched_barrier(0);
    }

    // ---- epilogue: token = m*16+lr (col), dims = wid*48 + nj*16 + lq*4 + r (rows)
    f32x4 b2v[3];
#pragma unroll
    for (int nj = 0; nj < 3; ++nj)
        b2v[nj] = *(const f32x4*)&b2[e * DIM + wid * 48 + nj * 16 + lq * 4];
#pragma unroll
    for (int m = 0; m < 8; ++m) {
        int row = m * 16 + lr;
        int ent = ents[row];
        if (ent >= 0) {
            float wv = wrow[row];
            int tok = ent >> 1;
            unsigned short* yb = (ent & 1) ? y1 : y0;
#pragma unroll
            for (int nj = 0; nj < 3; ++nj) {
                u16x4 pk;
#pragma unroll
                for (int r = 0; r < 4; ++r)
                    pk[r] = f2bf((Yacc[nj][m][r] + b2v[nj][r]) * wv);
                *(u16x4*)(yb + (size_t)tok * DIM + wid * 48 + nj * 16 + lq * 4) = pk;
            }
        }
    }
}

// ---------- K4: out = input + layer_scale[c] * (y0 + y1), NHWC->NCHW ----------
__global__ __launch_bounds__(256) void k_final(const float* __restrict__ input,
                                               const float* __restrict__ ls,
                                               const unsigned short* __restrict__ y0,
                                               const unsigned short* __restrict__ y1,
                                               float* __restrict__ out) {
    int b = blockIdx.x;
    int ct = b % 12;
    int hwt = (b / 12) % 32;
    int n = b / (12 * 32);
    int c0 = ct * 32, hw0 = hwt * 32;
    __shared__ float t[32][33];
    int tid = threadIdx.x;
    int t0 = n * HW + hw0;
#pragma unroll
    for (int k = 0; k < 2; ++k) {
        int idx = k * 256 + tid;
        int tl = idx >> 4, pr = idx & 15;       // 32 tokens x 16 col-pairs
        size_t o = (size_t)(t0 + tl) * DIM + c0 + pr * 2;
        unsigned int a = *(const unsigned int*)(y0 + o);
        unsigned int c = *(const unsigned int*)(y1 + o);
        t[tl][pr * 2]     = bf2f((unsigned short)a) + bf2f((unsigned short)c);
        t[tl][pr * 2 + 1] = bf2f((unsigned short)(a >> 16)) + bf2f((unsigned short)(c >> 16));
    }
    __syncthreads();
#pragma unroll
    for (int k = 0; k < 4; ++k) {
        int idx = k * 256 + tid;
        int cl = idx >> 5, j = idx & 31;
        size_t o = ((size_t)n * DIM + c0 + cl) * HW + hw0 + j;
        out[o] = input[o] + ls[c0 + cl] * t[j][cl];
    }
}

// ---------- launch ----------
extern "C" void kernel_launch(void* const* d_in, const int* in_sizes, int n_in,
                              void* d_out, int out_size, void* d_ws, size_t ws_size,
                              hipStream_t stream) {
    const float* input  = (const float*)d_in[0];
    const float* dw_w   = (const float*)d_in[1];
    const float* dw_b   = (const float*)d_in[2];
    const float* ln_g   = (const float*)d_in[3];
    const float* ln_b   = (const float*)d_in[4];
    const float* gate_w = (const float*)d_in[5];
    const float* w1     = (const float*)d_in[6];
    const float* b1     = (const float*)d_in[7];
    const float* w2     = (const float*)d_in[8];
    const float* b2     = (const float*)d_in[9];
    const float* lscale = (const float*)d_in[10];

    // ws layout (bytes)
    const size_t SZ_PLANE = (size_t)NB * DIM * HW * 4;      // 50,331,648 (xconv fp32)
    const size_t SZ_YBF   = (size_t)T_TOK * DIM * 2;        // 25,165,824 (y bf16)
    const size_t SZ_LNB   = (size_t)T_TOK * DIM;            // 12,582,912 (X fp8)
    const size_t SZ_W1    = (size_t)NE * DIM * HID;         //  4,718,592 (fp8)
    char* ws = (char*)d_ws;
    float* xconv = (float*)(ws + 0);                        // dead after k_ln_gate
    unsigned short* y0 = (unsigned short*)(ws + 0);         // overlays xconv
    unsigned short* y1 = (unsigned short*)(ws + SZ_YBF);    // still inside xconv region
    unsigned char* lnb = (unsigned char*)(ws + SZ_PLANE);
    unsigned char* w1t = (unsigned char*)(ws + SZ_PLANE + SZ_LNB);
    unsigned char* w2t = (unsigned char*)(ws + SZ_PLANE + SZ_LNB + SZ_W1);
    int*   lists  = (int*)(ws + SZ_PLANE + SZ_LNB + 2 * SZ_W1);
    float* wgt    = (float*)(ws + SZ_PLANE + SZ_LNB + 2 * SZ_W1 + 1048576);
    int*   counts = (int*)(ws + SZ_PLANE + SZ_LNB + 2 * SZ_W1 + 2 * 1048576);
    const size_t needed = SZ_PLANE + SZ_LNB + 2 * SZ_W1 + 2 * 1048576 + 256;
    if (ws_size < needed) return;

    hipMemsetAsync(counts, 0, 32, stream);
    k_transpose8<<<8 * 12 * 48, 256, 0, stream>>>(w1, w1t, DIM, HID);
    k_transpose8<<<8 * 48 * 12, 256, 0, stream>>>(w2, w2t, HID, DIM);
    k_conv<<<NB * DIM, 256, 0, stream>>>(input, dw_w, dw_b, xconv);
    k_ln_gate<<<T_TOK / 32, 256, 0, stream>>>(xconv, ln_g, ln_b, gate_w, lnb, lists, wgt, counts);
    k_moe<<<NE * 256, 512, 0, stream>>>(lnb, w1t, w2t, b1, b2, lists, wgt, counts, y0, y1);
    k_final<<<NB * 32 * 12, 256, 0, stream>>>(input, lscale, y0, y1, (float*)d_out);
}